// Round 4
// baseline (217.606 us; speedup 1.0000x reference)
//
#include <hip/hip_runtime.h>

// PolyLinear: out[i] = b + sum_j W[j] * prod_k x_aug[i, idx[j,k]]
// Deterministic lex-order enumeration: deg1 W[0..31], deg2 W[32..559] (a<=b),
// deg3 W[560..6543] (a<=b<=c). Factorization per row:
//   acc = sum_a W1[a]*x_a
//       + sum_{a<=b} (x_a*x_b) * ( W2[a,b] + sum_{c>=b} W3[a,b,c]*x_c )
//
// V5 vs V4 (~12 us kernel est): V4 was bound by a mix of (a) LDS-read insts
// (8 waves/CU x distinct 884-float parts = ~2300 ds_read insts/CU), (b) I$
// thrash (8 waves x distinct ~21KB unrolled code = 170KB unique straight-line
// code per CU vs 32KB L1I), (c) 2 waves/SIMD latency exposure.
// V5: all 8 waves of a block run the SAME part (one ~16KB code path per CU,
// L1I-resident; NPART=16) on disjoint rows, 4 rows/lane (4 indep FMA chains
// per weight -> LDS insts/CU halve to ~900, ILP covers FMA latency).
// Block covers 2048 rows of one part; 16 parts x 16 row-tiles = 256 blocks.
// Cross-part sum via atomicAdd on out (16/row), out zeroed by hipMemsetAsync.
// Expected: VALU-bound ~3us + epilogue -> kernel ~5-7us.

#define NPART 16
#define TOTAL3 5984

__device__ __forceinline__ constexpr int off2(int a, int b) {
    // deg2 base 32; pairs (a<=b) lex order
    return 32 + 32 * a - (a * (a - 1)) / 2 + (b - a);
}

__device__ __forceinline__ constexpr int off3(int a, int b, int c) {
    // deg3 base 560; triples (a<=b<=c) lex order.
    // g3[a] = #triples with first index < a
    constexpr int g3[32] = {
        0,    528,  1024, 1489, 1924, 2330, 2708, 3059,
        3384, 3684, 3960, 4213, 4444, 4654, 4844, 5015,
        5168, 5304, 5424, 5529, 5620, 5698, 5764, 5819,
        5864, 5900, 5928, 5949, 5964, 5974, 5980, 5983};
    return 560 + g3[a] + 32 * (b - a) - ((b * (b - 1)) / 2 - (a * (a - 1)) / 2) + (c - b);
}

// #deg3 triples strictly before pair (a,b)'s c-run in lex order
__device__ __forceinline__ constexpr int cum3(int a, int b) {
    return off3(a, b, b) - 560;
}

// Balanced static ownership of pair (a,b): parts get ~equal deg3-FMA counts.
__device__ __forceinline__ constexpr int owner_of(int a, int b) {
    return (cum3(a, b) * NPART) / TOTAL3;  // monotone, 0..NPART-1
}

template <int PART>
__device__ __forceinline__ void eval_part4(const float* __restrict__ Wl,
                                           const float (&x0)[32],
                                           const float (&x1)[32],
                                           const float (&x2)[32],
                                           const float (&x3)[32],
                                           float& r0, float& r1,
                                           float& r2, float& r3) {
    float a0 = 0.0f, a1 = 0.0f, a2 = 0.0f, a3 = 0.0f;
#pragma unroll
    for (int a = 0; a < 32; ++a) {
#pragma unroll
        for (int b = a; b < 32; ++b) {
            if (owner_of(a, b) == PART) {  // compile-time filter
                if (a == b) {  // attach deg1 term for feature a here
                    const float w1 = Wl[a];
                    a0 = __builtin_fmaf(w1, x0[a], a0);
                    a1 = __builtin_fmaf(w1, x1[a], a1);
                    a2 = __builtin_fmaf(w1, x2[a], a2);
                    a3 = __builtin_fmaf(w1, x3[a], a3);
                }
                const float w2 = Wl[off2(a, b)];  // deg2 weight seeds chains
                float s0 = w2, s1 = w2, s2 = w2, s3 = w2;
#pragma unroll
                for (int c = b; c < 32; ++c) {
                    const float w = Wl[off3(a, b, c)];  // 1 LDS read, 4 FMAs
                    s0 = __builtin_fmaf(w, x0[c], s0);
                    s1 = __builtin_fmaf(w, x1[c], s1);
                    s2 = __builtin_fmaf(w, x2[c], s2);
                    s3 = __builtin_fmaf(w, x3[c], s3);
                }
                a0 = __builtin_fmaf(x0[a] * x0[b], s0, a0);
                a1 = __builtin_fmaf(x1[a] * x1[b], s1, a1);
                a2 = __builtin_fmaf(x2[a] * x2[b], s2, a2);
                a3 = __builtin_fmaf(x3[a] * x3[b], s3, a3);
            }
        }
    }
    r0 = a0; r1 = a1; r2 = a2; r3 = a3;
}

// Block: 512 threads = 8 waves, ALL running the same part PART = bid & 15
// on 2048 disjoint rows (wave w owns rows tile+w*256+{0,64,128,192}+lane).
// No intra-block reduce; cross-part reduce via atomicAdd (out pre-zeroed).
__global__ __launch_bounds__(512, 1) void PolyLinear_40218073760341_kernel(
    const float* __restrict__ X,   // (rows, 32)
    const float* __restrict__ W,   // (6544,)
    const float* __restrict__ Bp,  // (1,)
    float* __restrict__ out)       // (rows,) — pre-zeroed
{
    const int lane = threadIdx.x & 63;
    const int wave = threadIdx.x >> 6;
    const int part = blockIdx.x & (NPART - 1);
    const long row0 = (long)(blockIdx.x >> 4) * 2048 + wave * 256 + lane;

    __shared__ float Wl[6544];  // 26.2 KB staged weights

    // Stage W -> LDS (coalesced float4; 1636 vec4 over 512 threads)
    {
        const float4* Wg = (const float4*)W;
        float4* Wd = (float4*)Wl;
        for (int i = threadIdx.x; i < 1636; i += 512) Wd[i] = Wg[i];
    }

    // Load this lane's 4 rows into registers (coalesced float4 per wave).
    float x0[32], x1[32], x2[32], x3[32];
    {
        const float4* p0 = (const float4*)(X + (row0)*32);
        const float4* p1 = (const float4*)(X + (row0 + 64) * 32);
        const float4* p2 = (const float4*)(X + (row0 + 128) * 32);
        const float4* p3 = (const float4*)(X + (row0 + 192) * 32);
#pragma unroll
        for (int i = 0; i < 8; ++i) {
            const float4 a = p0[i];
            x0[4 * i + 0] = a.x; x0[4 * i + 1] = a.y;
            x0[4 * i + 2] = a.z; x0[4 * i + 3] = a.w;
            const float4 b = p1[i];
            x1[4 * i + 0] = b.x; x1[4 * i + 1] = b.y;
            x1[4 * i + 2] = b.z; x1[4 * i + 3] = b.w;
            const float4 c = p2[i];
            x2[4 * i + 0] = c.x; x2[4 * i + 1] = c.y;
            x2[4 * i + 2] = c.z; x2[4 * i + 3] = c.w;
            const float4 d = p3[i];
            x3[4 * i + 0] = d.x; x3[4 * i + 1] = d.y;
            x3[4 * i + 2] = d.z; x3[4 * i + 3] = d.w;
        }
    }
    __syncthreads();  // Wl ready

    float r0 = 0.0f, r1 = 0.0f, r2 = 0.0f, r3 = 0.0f;
#define EVAL_CASE(P) \
    case P: eval_part4<P>(Wl, x0, x1, x2, x3, r0, r1, r2, r3); break;
    switch (part) {
        EVAL_CASE(0)  EVAL_CASE(1)  EVAL_CASE(2)  EVAL_CASE(3)
        EVAL_CASE(4)  EVAL_CASE(5)  EVAL_CASE(6)  EVAL_CASE(7)
        EVAL_CASE(8)  EVAL_CASE(9)  EVAL_CASE(10) EVAL_CASE(11)
        EVAL_CASE(12) EVAL_CASE(13) EVAL_CASE(14) EVAL_CASE(15)
    }
#undef EVAL_CASE

    // Bias added exactly once per row (by the part-0 block covering it).
    const float badd = (part == 0) ? Bp[0] : 0.0f;
    atomicAdd(&out[row0], r0 + badd);
    atomicAdd(&out[row0 + 64], r1 + badd);
    atomicAdd(&out[row0 + 128], r2 + badd);
    atomicAdd(&out[row0 + 192], r3 + badd);
}

extern "C" void kernel_launch(void* const* d_in, const int* in_sizes, int n_in,
                              void* d_out, int out_size, void* d_ws, size_t ws_size,
                              hipStream_t stream) {
    const float* X  = (const float*)d_in[0];  // (32768, 32) fp32
    const float* W  = (const float*)d_in[1];  // (1, 6544) fp32
    const float* Bp = (const float*)d_in[2];  // (1,) fp32
    // d_in[3] = idx — deterministic, unused.
    float* out = (float*)d_out;

    const int rows = in_sizes[0] / 32;  // 32768
    hipMemsetAsync(out, 0, (size_t)rows * sizeof(float), stream);
    const int grid = (rows / 2048) * NPART;  // 16 tiles x 16 parts = 256
    PolyLinear_40218073760341_kernel<<<grid, 512, 0, stream>>>(X, W, Bp, out);
}

// Round 5
// 139.406 us; speedup vs baseline: 1.5610x; 1.5610x over previous
//
#include <hip/hip_runtime.h>

// PolyLinear: out[i] = b + sum_j W[j] * prod_k x_aug[i, idx[j,k]]
// Deterministic lex-order enumeration: deg1 W[0..31], deg2 W[32..559] (a<=b),
// deg3 W[560..6543] (a<=b<=c). Factorization per row:
//   acc = sum_a W1[a]*x_a
//       + sum_{a<=b} (x_a*x_b) * ( W2[a,b] + sum_{c>=b} W3[a,b,c]*x_c )
//
// V6 vs V5 (154 us warm, spilled): V5's structure was right but 512-thr
// blocks get a hard 128-VGPR allocation (allocator targets 2 resident
// blocks/CU REGARDLESS of launch_bounds min-waves: 1024thr->64, 512thr->128
// observed across V2-V5), while 4 rows/lane needs 128 VGPRs for x alone.
// V6: 256-thr blocks (4 waves) -> 256-VGPR cap (m97 precedent: 164 VGPR).
// All 4 waves run the SAME part (one ~19KB code path per block), 4 rows/lane
// (LDS b128 insts/CU = 3536/R = 884 ~ 4.4us; VALU floor 3.0us), NPART=16,
// grid = 32 row-tiles x 16 parts = 512 blocks = 2 blocks/CU = 2 waves/SIMD.
// Cross-part reduce via atomicAdd on pre-zeroed out.

#define NPART 16
#define TOTAL3 5984

__device__ __forceinline__ constexpr int off2(int a, int b) {
    // deg2 base 32; pairs (a<=b) lex order
    return 32 + 32 * a - (a * (a - 1)) / 2 + (b - a);
}

__device__ __forceinline__ constexpr int off3(int a, int b, int c) {
    // deg3 base 560; triples (a<=b<=c) lex order.
    // g3[a] = #triples with first index < a
    constexpr int g3[32] = {
        0,    528,  1024, 1489, 1924, 2330, 2708, 3059,
        3384, 3684, 3960, 4213, 4444, 4654, 4844, 5015,
        5168, 5304, 5424, 5529, 5620, 5698, 5764, 5819,
        5864, 5900, 5928, 5949, 5964, 5974, 5980, 5983};
    return 560 + g3[a] + 32 * (b - a) - ((b * (b - 1)) / 2 - (a * (a - 1)) / 2) + (c - b);
}

// #deg3 triples strictly before pair (a,b)'s c-run in lex order
__device__ __forceinline__ constexpr int cum3(int a, int b) {
    return off3(a, b, b) - 560;
}

// Balanced static ownership of pair (a,b): parts get ~equal deg3-FMA counts.
__device__ __forceinline__ constexpr int owner_of(int a, int b) {
    return (cum3(a, b) * NPART) / TOTAL3;  // monotone, 0..NPART-1
}

template <int PART>
__device__ __forceinline__ void eval_part4(const float* __restrict__ Wl,
                                           const float (&x0)[32],
                                           const float (&x1)[32],
                                           const float (&x2)[32],
                                           const float (&x3)[32],
                                           float& r0, float& r1,
                                           float& r2, float& r3) {
    float a0 = 0.0f, a1 = 0.0f, a2 = 0.0f, a3 = 0.0f;
#pragma unroll
    for (int a = 0; a < 32; ++a) {
#pragma unroll
        for (int b = a; b < 32; ++b) {
            if (owner_of(a, b) == PART) {  // compile-time filter
                if (a == b) {  // attach deg1 term for feature a here
                    const float w1 = Wl[a];
                    a0 = __builtin_fmaf(w1, x0[a], a0);
                    a1 = __builtin_fmaf(w1, x1[a], a1);
                    a2 = __builtin_fmaf(w1, x2[a], a2);
                    a3 = __builtin_fmaf(w1, x3[a], a3);
                }
                const float w2 = Wl[off2(a, b)];  // deg2 weight seeds chains
                float s0 = w2, s1 = w2, s2 = w2, s3 = w2;
#pragma unroll
                for (int c = b; c < 32; ++c) {
                    const float w = Wl[off3(a, b, c)];  // 1 LDS read, 4 FMAs
                    s0 = __builtin_fmaf(w, x0[c], s0);
                    s1 = __builtin_fmaf(w, x1[c], s1);
                    s2 = __builtin_fmaf(w, x2[c], s2);
                    s3 = __builtin_fmaf(w, x3[c], s3);
                }
                a0 = __builtin_fmaf(x0[a] * x0[b], s0, a0);
                a1 = __builtin_fmaf(x1[a] * x1[b], s1, a1);
                a2 = __builtin_fmaf(x2[a] * x2[b], s2, a2);
                a3 = __builtin_fmaf(x3[a] * x3[b], s3, a3);
            }
        }
    }
    r0 = a0; r1 = a1; r2 = a2; r3 = a3;
}

// Block: 256 threads = 4 waves, ALL running the same part (bid & 15) on
// 1024 disjoint rows: thread t owns rows tile*1024 + r*256 + t, r=0..3.
// No intra-block reduce; cross-part reduce via atomicAdd (out pre-zeroed).
__global__ __launch_bounds__(256) void PolyLinear_40218073760341_kernel(
    const float* __restrict__ X,   // (rows, 32)
    const float* __restrict__ W,   // (6544,)
    const float* __restrict__ Bp,  // (1,)
    float* __restrict__ out)       // (rows,) — pre-zeroed
{
    const int part = blockIdx.x & (NPART - 1);
    const long rbase = (long)(blockIdx.x >> 4) * 1024 + threadIdx.x;

    __shared__ float Wl[6544];  // 26.2 KB staged weights

    // Stage W -> LDS (coalesced float4; 1636 vec4 over 256 threads)
    {
        const float4* Wg = (const float4*)W;
        float4* Wd = (float4*)Wl;
        for (int i = threadIdx.x; i < 1636; i += 256) Wd[i] = Wg[i];
    }

    // Load this thread's 4 rows into registers (coalesced float4 per wave).
    float x0[32], x1[32], x2[32], x3[32];
    {
        const float4* p0 = (const float4*)(X + (rbase) * 32);
        const float4* p1 = (const float4*)(X + (rbase + 256) * 32);
        const float4* p2 = (const float4*)(X + (rbase + 512) * 32);
        const float4* p3 = (const float4*)(X + (rbase + 768) * 32);
#pragma unroll
        for (int i = 0; i < 8; ++i) {
            const float4 a = p0[i];
            x0[4 * i + 0] = a.x; x0[4 * i + 1] = a.y;
            x0[4 * i + 2] = a.z; x0[4 * i + 3] = a.w;
            const float4 b = p1[i];
            x1[4 * i + 0] = b.x; x1[4 * i + 1] = b.y;
            x1[4 * i + 2] = b.z; x1[4 * i + 3] = b.w;
            const float4 c = p2[i];
            x2[4 * i + 0] = c.x; x2[4 * i + 1] = c.y;
            x2[4 * i + 2] = c.z; x2[4 * i + 3] = c.w;
            const float4 d = p3[i];
            x3[4 * i + 0] = d.x; x3[4 * i + 1] = d.y;
            x3[4 * i + 2] = d.z; x3[4 * i + 3] = d.w;
        }
    }
    __syncthreads();  // Wl ready

    float r0 = 0.0f, r1 = 0.0f, r2 = 0.0f, r3 = 0.0f;
#define EVAL_CASE(P) \
    case P: eval_part4<P>(Wl, x0, x1, x2, x3, r0, r1, r2, r3); break;
    switch (part) {
        EVAL_CASE(0)  EVAL_CASE(1)  EVAL_CASE(2)  EVAL_CASE(3)
        EVAL_CASE(4)  EVAL_CASE(5)  EVAL_CASE(6)  EVAL_CASE(7)
        EVAL_CASE(8)  EVAL_CASE(9)  EVAL_CASE(10) EVAL_CASE(11)
        EVAL_CASE(12) EVAL_CASE(13) EVAL_CASE(14) EVAL_CASE(15)
    }
#undef EVAL_CASE

    // Bias added exactly once per row (by the part-0 block covering it).
    const float badd = (part == 0) ? Bp[0] : 0.0f;
    atomicAdd(&out[rbase], r0 + badd);
    atomicAdd(&out[rbase + 256], r1 + badd);
    atomicAdd(&out[rbase + 512], r2 + badd);
    atomicAdd(&out[rbase + 768], r3 + badd);
}

extern "C" void kernel_launch(void* const* d_in, const int* in_sizes, int n_in,
                              void* d_out, int out_size, void* d_ws, size_t ws_size,
                              hipStream_t stream) {
    const float* X  = (const float*)d_in[0];  // (32768, 32) fp32
    const float* W  = (const float*)d_in[1];  // (1, 6544) fp32
    const float* Bp = (const float*)d_in[2];  // (1,) fp32
    // d_in[3] = idx — deterministic, unused.
    float* out = (float*)d_out;

    const int rows = in_sizes[0] / 32;  // 32768
    hipMemsetAsync(out, 0, (size_t)rows * sizeof(float), stream);
    const int grid = (rows / 1024) * NPART;  // 32 tiles x 16 parts = 512
    PolyLinear_40218073760341_kernel<<<grid, 256, 0, stream>>>(X, W, Bp, out);
}

// Round 6
// 96.704 us; speedup vs baseline: 2.2502x; 1.4416x over previous
//
#include <hip/hip_runtime.h>

// PolyLinear: out[i] = b + sum_j W[j] * prod_k x_aug[i, idx[j,k]]
// Deterministic lex-order enumeration: deg1 W[0..31], deg2 W[32..559] (a<=b),
// deg3 W[560..6543] (a<=b<=c). Factorization per row:
//   acc = sum_a W1[a]*x_a
//       + sum_{a<=b} (x_a*x_b) * ( W2[a,b] + sum_{c>=b} W3[a,b,c]*x_c )
//
// V7 vs V6 (82 us warm, spilled at VGPR=256): every R=4 variant that
// delivered weights through vector pipes spilled — ds_read_b128 results
// need VGPR destinations, the scheduler batches several pairs' reads, and
// transient pressure (x[128] + in-flight weight quads) blew every cap.
// V7 moves weights to the SCALAR pipe: read W directly from global with
// wave-uniform compile-time offsets -> compiler emits s_load_dwordx16 into
// SGPRs -> v_fmac_f32 with SGPR weight operand. Zero VGPR cost for weights,
// no LDS at all. V1 proved the pattern but at R=1 (1 FMA/weight, drain-
// dominated); at R=4 each pair = 2 s_load_dwordx16 feeding 128 FMAs
// (~256 cy VALU) -> SMEM latency amortized/hidden.
// Geometry: 256-thr blocks (4 waves, ALL same part -> one ~12KB code path,
// L1I-resident; part weights 1.7KB, scalar-cache-resident), R=4 rows/thread,
// NPART=16, grid = 32 tiles x 16 parts = 512 blocks = 2/CU, 2 waves/SIMD.
// Cross-part reduce via atomicAdd on pre-zeroed out.
// Budget: VALU floor 3.0us; expect kernel ~4-7us.

#define NPART 16
#define TOTAL3 5984

__device__ __forceinline__ constexpr int off2(int a, int b) {
    // deg2 base 32; pairs (a<=b) lex order
    return 32 + 32 * a - (a * (a - 1)) / 2 + (b - a);
}

__device__ __forceinline__ constexpr int off3(int a, int b, int c) {
    // deg3 base 560; triples (a<=b<=c) lex order.
    // g3[a] = #triples with first index < a
    constexpr int g3[32] = {
        0,    528,  1024, 1489, 1924, 2330, 2708, 3059,
        3384, 3684, 3960, 4213, 4444, 4654, 4844, 5015,
        5168, 5304, 5424, 5529, 5620, 5698, 5764, 5819,
        5864, 5900, 5928, 5949, 5964, 5974, 5980, 5983};
    return 560 + g3[a] + 32 * (b - a) - ((b * (b - 1)) / 2 - (a * (a - 1)) / 2) + (c - b);
}

// #deg3 triples strictly before pair (a,b)'s c-run in lex order
__device__ __forceinline__ constexpr int cum3(int a, int b) {
    return off3(a, b, b) - 560;
}

// Balanced static ownership of pair (a,b): parts get ~equal deg3-FMA counts.
__device__ __forceinline__ constexpr int owner_of(int a, int b) {
    return (cum3(a, b) * NPART) / TOTAL3;  // monotone, 0..NPART-1
}

template <int PART>
__device__ __forceinline__ void eval_part4(const float* __restrict__ W,
                                           const float (&x0)[32],
                                           const float (&x1)[32],
                                           const float (&x2)[32],
                                           const float (&x3)[32],
                                           float& r0, float& r1,
                                           float& r2, float& r3) {
    float a0 = 0.0f, a1 = 0.0f, a2 = 0.0f, a3 = 0.0f;
#pragma unroll
    for (int a = 0; a < 32; ++a) {
#pragma unroll
        for (int b = a; b < 32; ++b) {
            if (owner_of(a, b) == PART) {  // compile-time filter
                if (a == b) {  // attach deg1 term for feature a here
                    const float w1 = W[a];  // uniform -> s_load
                    a0 = __builtin_fmaf(w1, x0[a], a0);
                    a1 = __builtin_fmaf(w1, x1[a], a1);
                    a2 = __builtin_fmaf(w1, x2[a], a2);
                    a3 = __builtin_fmaf(w1, x3[a], a3);
                }
                const float w2 = W[off2(a, b)];  // uniform -> s_load
                float s0 = w2, s1 = w2, s2 = w2, s3 = w2;
#pragma unroll
                for (int c = b; c < 32; ++c) {
                    // Uniform, consecutive offsets -> s_load_dwordx16 batches
                    // into SGPRs; FMA consumes the SGPR operand directly.
                    const float w = W[off3(a, b, c)];
                    s0 = __builtin_fmaf(w, x0[c], s0);
                    s1 = __builtin_fmaf(w, x1[c], s1);
                    s2 = __builtin_fmaf(w, x2[c], s2);
                    s3 = __builtin_fmaf(w, x3[c], s3);
                }
                a0 = __builtin_fmaf(x0[a] * x0[b], s0, a0);
                a1 = __builtin_fmaf(x1[a] * x1[b], s1, a1);
                a2 = __builtin_fmaf(x2[a] * x2[b], s2, a2);
                a3 = __builtin_fmaf(x3[a] * x3[b], s3, a3);
            }
        }
    }
    r0 = a0; r1 = a1; r2 = a2; r3 = a3;
}

// Block: 256 threads = 4 waves, ALL running the same part (bid & 15) on
// 1024 disjoint rows: thread t owns rows tile*1024 + r*256 + t, r=0..3.
// No LDS; weights ride the scalar pipe. Cross-part reduce via atomicAdd.
__global__ __launch_bounds__(256) void PolyLinear_40218073760341_kernel(
    const float* __restrict__ X,   // (rows, 32)
    const float* __restrict__ W,   // (6544,)
    const float* __restrict__ Bp,  // (1,)
    float* __restrict__ out)       // (rows,) — pre-zeroed
{
    const int part = blockIdx.x & (NPART - 1);
    const long rbase = (long)(blockIdx.x >> 4) * 1024 + threadIdx.x;

    // Load this thread's 4 rows into registers (coalesced float4 per wave).
    float x0[32], x1[32], x2[32], x3[32];
    {
        const float4* p0 = (const float4*)(X + (rbase) * 32);
        const float4* p1 = (const float4*)(X + (rbase + 256) * 32);
        const float4* p2 = (const float4*)(X + (rbase + 512) * 32);
        const float4* p3 = (const float4*)(X + (rbase + 768) * 32);
#pragma unroll
        for (int i = 0; i < 8; ++i) {
            const float4 a = p0[i];
            x0[4 * i + 0] = a.x; x0[4 * i + 1] = a.y;
            x0[4 * i + 2] = a.z; x0[4 * i + 3] = a.w;
            const float4 b = p1[i];
            x1[4 * i + 0] = b.x; x1[4 * i + 1] = b.y;
            x1[4 * i + 2] = b.z; x1[4 * i + 3] = b.w;
            const float4 c = p2[i];
            x2[4 * i + 0] = c.x; x2[4 * i + 1] = c.y;
            x2[4 * i + 2] = c.z; x2[4 * i + 3] = c.w;
            const float4 d = p3[i];
            x3[4 * i + 0] = d.x; x3[4 * i + 1] = d.y;
            x3[4 * i + 2] = d.z; x3[4 * i + 3] = d.w;
        }
    }

    float r0 = 0.0f, r1 = 0.0f, r2 = 0.0f, r3 = 0.0f;
#define EVAL_CASE(P) \
    case P: eval_part4<P>(W, x0, x1, x2, x3, r0, r1, r2, r3); break;
    switch (part) {
        EVAL_CASE(0)  EVAL_CASE(1)  EVAL_CASE(2)  EVAL_CASE(3)
        EVAL_CASE(4)  EVAL_CASE(5)  EVAL_CASE(6)  EVAL_CASE(7)
        EVAL_CASE(8)  EVAL_CASE(9)  EVAL_CASE(10) EVAL_CASE(11)
        EVAL_CASE(12) EVAL_CASE(13) EVAL_CASE(14) EVAL_CASE(15)
    }
#undef EVAL_CASE

    // Bias added exactly once per row (by the part-0 block covering it).
    const float badd = (part == 0) ? Bp[0] : 0.0f;
    atomicAdd(&out[rbase], r0 + badd);
    atomicAdd(&out[rbase + 256], r1 + badd);
    atomicAdd(&out[rbase + 512], r2 + badd);
    atomicAdd(&out[rbase + 768], r3 + badd);
}

extern "C" void kernel_launch(void* const* d_in, const int* in_sizes, int n_in,
                              void* d_out, int out_size, void* d_ws, size_t ws_size,
                              hipStream_t stream) {
    const float* X  = (const float*)d_in[0];  // (32768, 32) fp32
    const float* W  = (const float*)d_in[1];  // (1, 6544) fp32
    const float* Bp = (const float*)d_in[2];  // (1,) fp32
    // d_in[3] = idx — deterministic, unused.
    float* out = (float*)d_out;

    const int rows = in_sizes[0] / 32;  // 32768
    hipMemsetAsync(out, 0, (size_t)rows * sizeof(float), stream);
    const int grid = (rows / 1024) * NPART;  // 32 tiles x 16 parts = 512
    PolyLinear_40218073760341_kernel<<<grid, 256, 0, stream>>>(X, W, Bp, out);
}